// Round 20
// baseline (118.145 us; speedup 1.0000x reference)
//
#include <hip/hip_runtime.h>
#include <math.h>

#define VOCAB 50000
#define EMBED 128
#define SEQ   200
#define HID   30
#define BATCH 4096

// LEDGER: rnn champion = r18 (permlane exchange, ~71.5us). r17 DPP-quad and
// r19 zero-LDS-DPP both regressed (dependent-position DPP + hazard states).
// UNKNOWN: the ~22us total-minus-rnn gap attributed to embproj was never
// measured (embproj never ranks in top-5). THIS ROUND: rnn=r18 verbatim,
// embproj=r16 verbatim, PLUS embproj_v2 launched FIRST with its output
// overwritten by v1 -> v2 duration = total delta, zero correctness risk.
typedef float4 __attribute__((__may_alias__)) f4ma;
typedef unsigned int uint2v __attribute__((ext_vector_type(2)));

__device__ __forceinline__ float tanh_fast(float x) {
    float e = __expf(2.0f * x);
    return 1.0f - __fdividef(2.0f, e + 1.0f);
}
__device__ __forceinline__ float swz16_f(float x) {   // lane ^= 16
    return __int_as_float(__builtin_amdgcn_ds_swizzle(__float_as_int(x), 0x401F));
}

// CANDIDATE embproj_v2 (being timed this round; output overwritten by v1).
// Lane (j16 = l&15, p = (l>>4)&1 -> own col j16+16p AND k-half 64p,
// g = l>>5 -> row-in-pair). 2 rows per 16-load pass (4 distinct 256B
// segments/pass vs v1's 2 -> half the VMEM instructions per row).
// Exchange = r16-rnn-proven swz16 send=p?pA:pB pattern.
__global__ __launch_bounds__(256, 2) void embproj_v2(
    const float* __restrict__ emb, const float* __restrict__ Wx,
    const float* __restrict__ brnn, float* __restrict__ embP)
{
    int tid  = threadIdx.x;
    int wid  = blockIdx.x * 4 + (tid >> 6);   // 0..2047
    int l    = tid & 63;
    int j16  = l & 15;
    int p    = (l >> 4) & 1;
    int g    = l >> 5;
    int jown = j16 + 16 * p;
    int jc   = (jown < HID) ? jown : HID - 1;
    int cB   = (j16 + 16 < HID) ? (j16 + 16) : HID - 1;
    int k0   = 64 * p;

    int base = wid * 26;
    if (base >= VOCAB) return;

    float whxA[64], whxB[64];
    #pragma unroll
    for (int i = 0; i < 64; ++i) {
        whxA[i] = Wx[(k0 + i) * HID + j16];   // col j16 < 16 (always valid)
        whxB[i] = Wx[(k0 + i) * HID + cB];    // col j16+16 (clamped)
    }
    float bj = brnn[jc];

    for (int r = 0; r < 26; r += 2) {
        int v  = base + r + g;                // this lane's row
        int vc = min(v, VOCAB - 1);
        const f4ma* e4 = (const f4ma*)(emb + (size_t)vc * EMBED + k0);
        float4 er[16];
        #pragma unroll
        for (int q = 0; q < 16; ++q) er[q] = e4[q];

        float a0=0.f,a1=0.f,a2=0.f,a3=0.f, c0=0.f,c1=0.f,c2=0.f,c3=0.f;
        #pragma unroll
        for (int q = 0; q < 16; ++q) {
            a0 += er[q].x * whxA[4*q+0];  a1 += er[q].y * whxA[4*q+1];
            a2 += er[q].z * whxA[4*q+2];  a3 += er[q].w * whxA[4*q+3];
            c0 += er[q].x * whxB[4*q+0];  c1 += er[q].y * whxB[4*q+1];
            c2 += er[q].z * whxB[4*q+2];  c3 += er[q].w * whxB[4*q+3];
        }
        float pA = (a0 + a1) + (a2 + a3);     // col j16    , k-half p
        float pB = (c0 + c1) + (c2 + c3);     // col j16+16 , k-half p
        float own  = p ? pB : pA;
        float send = p ? pA : pB;             // partner (l^16) needs this
        float recv = swz16_f(send);
        float full = bj + (own + recv);
        if (jown < HID && v < VOCAB)
            embP[(size_t)v * HID + jown] = full;
    }
}

// Kernel 1: embproj v1 -- BYTE-IDENTICAL to r16-r18 (passed 4x). Runs AFTER
// v2 and overwrites embP with proven values. Do not touch.
__global__ __launch_bounds__(256, 2) void embproj_kernel(
    const float* __restrict__ emb, const float* __restrict__ Wx,
    const float* __restrict__ brnn, float* __restrict__ embP)
{
    int tid  = threadIdx.x;
    int wv   = tid >> 6;
    int l    = tid & 63;
    int j16  = l & 15;
    int p    = (l >> 4) & 1;
    int g    = l >> 5;
    int col  = j16 + 16 * g;
    int colc = (col < HID) ? col : (HID - 1);
    int k0   = 64 * p;

    float whx[64];
    #pragma unroll
    for (int i = 0; i < 64; ++i)
        whx[i] = Wx[(k0 + i) * HID + colc];
    float bj = brnn[colc];

    int base = (blockIdx.x * 4 + wv) * 25;

    float4 eA[16], eB[16];
    #define LOADROW(dst, v) { \
        int vc = min((v), VOCAB - 1); \
        const f4ma* e4 = (const f4ma*)(emb + (size_t)vc * EMBED + k0); \
        _Pragma("unroll") \
        for (int q = 0; q < 16; ++q) dst[q] = e4[q]; \
    }
    #define COMPUTE(src, v) { \
        float a0 = 0.f, a1 = 0.f, a2 = 0.f, a3 = 0.f; \
        _Pragma("unroll") \
        for (int q = 0; q < 16; ++q) { \
            a0 += src[q].x * whx[4*q+0]; \
            a1 += src[q].y * whx[4*q+1]; \
            a2 += src[q].z * whx[4*q+2]; \
            a3 += src[q].w * whx[4*q+3]; \
        } \
        float own  = (a0 + a1) + (a2 + a3); \
        float full = bj + (own + swz16_f(own)); \
        if (p == 0 && col < HID && (v) < VOCAB) \
            embP[(size_t)(v) * HID + col] = full; \
    }

    LOADROW(eA, base + 0);
    for (int r = 0; r < 25; r += 2) {
        LOADROW(eB, base + r + 1);
        COMPUTE(eA, base + r);
        LOADROW(eA, base + r + 2);
        COMPUTE(eB, base + r + 1);
    }
    #undef LOADROW
    #undef COMPUTE
}

// Kernel 2: fused RNN recurrence + dense head. BYTE-IDENTICAL to r18
// (champion, ~71.5us, absmax 0.0). Do not touch.
__global__ __launch_bounds__(128) void rnn_head_kernel(
    const int* __restrict__ tokens, const float* __restrict__ embP,
    const float* __restrict__ Wh,
    const float* __restrict__ W1, const float* __restrict__ b1,
    const float* __restrict__ W2, const float* __restrict__ b2,
    const float* __restrict__ W3, const float* __restrict__ b3,
    const float* __restrict__ Wo, const float* __restrict__ bo,
    float* __restrict__ out)
{
    __shared__ __align__(16) float hL[4][32];
    __shared__ float d1L[4][128];
    __shared__ float d2L[4][64];

    int tid  = threadIdx.x;
    int wv   = tid >> 6;            // wave 0..1
    int l    = tid & 63;
    int j16  = l & 15;
    int row  = (l >> 4) & 1;        // row within wave (bit 4)
    int p    = l >> 5;              // k-half (bit 5) -> partner = l^32
    int j    = j16 + 16 * p;        // own column
    int rloc = wv * 2 + row;        // row within block, 0..3
    int b    = blockIdx.x * 4 + rloc;

    const int* trow = tokens + (size_t)b * SEQ;
    int jc = (j < HID) ? j : (HID - 1);

    hL[rloc][j] = 0.0f;             // h0 = 0
    __builtin_amdgcn_sched_barrier(0);

    // permlane32_swap direction probe (r18-proven)
    bool useR0;
    {
        unsigned li = (unsigned)l;
        uint2v rp = __builtin_amdgcn_permlane32_swap(li, li, false, false);
        useR0 = (rp[0] == (unsigned)(l ^ 32));
    }

    int cB = j16 + 16;
    float whA[16], whB[16];
    #pragma unroll
    for (int kk = 0; kk < 16; ++kk) {
        int k = 16 * p + kk;
        whA[kk] = (k < HID) ? Wh[k * HID + j16] : 0.0f;
        whB[kk] = (k < HID && cB < HID) ? Wh[k * HID + cB] : 0.0f;
    }

    float xq[8]; int tr[8];
    #pragma unroll
    for (int s = 0; s < 8; ++s) {
        xq[s] = embP[(size_t)trow[s] * HID + jc];
        tr[s] = trow[8 + s];
    }

    for (int t = 0; t < SEQ; t += 8) {
        #pragma unroll
        for (int s = 0; s < 8; ++s) {
            float hv[16];
            const f4ma* h4 = (const f4ma*)(&hL[rloc][16 * p]);
            #pragma unroll
            for (int qq = 0; qq < 4; ++qq) {
                f4ma hh = h4[qq];
                hv[4*qq+0] = hh.x; hv[4*qq+1] = hh.y;
                hv[4*qq+2] = hh.z; hv[4*qq+3] = hh.w;
            }
            float xp = xq[s];
            xq[s] = embP[(size_t)tr[s] * HID + jc];
            int tn = t + 16 + s; tn = (tn < SEQ) ? tn : SEQ - 1;
            tr[s] = trow[tn];

            float a0=0.f, a1=0.f, b0=0.f, b1=0.f;
            #pragma unroll
            for (int kk = 0; kk < 16; kk += 2) {
                a0 += hv[kk]   * whA[kk];
                a1 += hv[kk+1] * whA[kk+1];
                b0 += hv[kk]   * whB[kk];
                b1 += hv[kk+1] * whB[kk+1];
            }
            float pA = a0 + a1;
            float pB = b0 + b1;
            float own  = p ? pB : pA;
            float send = p ? pA : pB;
            unsigned si = __float_as_uint(send);
            uint2v sw = __builtin_amdgcn_permlane32_swap(si, si, false, false);
            float recv = __uint_as_float(useR0 ? sw[0] : sw[1]);
            float hn = tanh_fast(xp + (own + recv));
            if (j < HID) hL[rloc][j] = hn;
            __builtin_amdgcn_sched_barrier(0);
        }
    }

    {
        int half = l >> 5, j32 = l & 31;
        int rh = wv * 2 + half;
        int bB = blockIdx.x * 4 + rh;
        #pragma unroll
        for (int qq = 0; qq < 4; ++qq) {
            int c = j32 + 32 * qq;
            float acc = b1[c];
            #pragma unroll
            for (int k = 0; k < HID; ++k) acc += hL[rh][k] * W1[k * 128 + c];
            d1L[rh][c] = fmaxf(acc, 0.0f);
        }
        #pragma unroll
        for (int qq = 0; qq < 2; ++qq) {
            int c = j32 + 32 * qq;
            float acc = b2[c];
            #pragma unroll 8
            for (int k = 0; k < 128; ++k) acc += d1L[rh][k] * W2[k * 64 + c];
            d2L[rh][c] = fmaxf(acc, 0.0f);
        }
        float acc3 = b3[j32];
        #pragma unroll 8
        for (int k = 0; k < 64; ++k) acc3 += d2L[rh][k] * W3[k * 32 + j32];
        acc3 = fmaxf(acc3, 0.0f);
        float prod = acc3 * Wo[j32];
        #pragma unroll
        for (int m = 16; m > 0; m >>= 1) prod += __shfl_xor(prod, m, 32);
        if (j32 == 0) out[bB] = 1.0f / (1.0f + __expf(-(prod + bo[0])));
    }
}

extern "C" void kernel_launch(void* const* d_in, const int* in_sizes, int n_in,
                              void* d_out, int out_size, void* d_ws, size_t ws_size,
                              hipStream_t stream) {
    (void)in_sizes; (void)n_in; (void)out_size; (void)ws_size;
    const int*   tokens = (const int*)  d_in[0];
    const float* emb    = (const float*)d_in[1];
    const float* Wx     = (const float*)d_in[2];
    const float* Wh     = (const float*)d_in[3];
    const float* brnn   = (const float*)d_in[4];
    const float* W1     = (const float*)d_in[5];
    const float* b1     = (const float*)d_in[6];
    const float* W2     = (const float*)d_in[7];
    const float* b2     = (const float*)d_in[8];
    const float* W3     = (const float*)d_in[9];
    const float* b3     = (const float*)d_in[10];
    const float* Wo     = (const float*)d_in[11];
    const float* bo     = (const float*)d_in[12];
    float* out  = (float*)d_out;
    float* embP = (float*)d_ws;   // 50000*30*4 = 6 MB

    // v2 first (being timed); v1 overwrites embP with proven values.
    embproj_v2<<<512, 256, 0, stream>>>(emb, Wx, brnn, embP);
    embproj_kernel<<<512, 256, 0, stream>>>(emb, Wx, brnn, embP);
    rnn_head_kernel<<<BATCH / 4, 128, 0, stream>>>(
        tokens, embP, Wh, W1, b1, W2, b2, W3, b3, Wo, bo, out);
}

// Round 21
// 108.324 us; speedup vs baseline: 1.0907x; 1.0907x over previous
//
#include <hip/hip_runtime.h>
#include <math.h>

#define VOCAB 50000
#define EMBED 128
#define SEQ   200
#define HID   30
#define BATCH 4096

// LEDGER: rnn champion = r18 (71.5us, absmax 0.0 x3). embproj measured
// ~22us across THREE different structures (r20 overwrite experiment:
// v2 = 22.3us despite half the VMEM instrs) -> instruction mix is NOT
// binding; the shared invariant is 2 resident waves/SIMD (VGPR-fat
// buffers) exposing ~600cyc L3 latency per row-pass.
// r21: v1's EXACT per-(v,j) FP sequence, but streamed loads (no eA/eB
// arrays), 6 rows/wave, launch_bounds(256,3) -> ~130 VGPR, 3 resident
// waves/SIMD, 8 scheduled/SIMD. rnn byte-frozen.
typedef float4 __attribute__((__may_alias__)) f4ma;
typedef unsigned int uint2v __attribute__((ext_vector_type(2)));

__device__ __forceinline__ float tanh_fast(float x) {
    float e = __expf(2.0f * x);
    return 1.0f - __fdividef(2.0f, e + 1.0f);
}
__device__ __forceinline__ float swz16_f(float x) {   // lane ^= 16
    return __int_as_float(__builtin_amdgcn_ds_swizzle(__float_as_int(x), 0x401F));
}

// Kernel 1: embP[v][j] = sum_e emb[v][e]*Wx[e][j] + b_rnn[j]
// Lane (j16 = l&15, p = (l>>4)&1, g = l>>5): col = j16+16g, k-half 64p.
// Per (v,j) FP sequence IDENTICAL to the r16-r20 v1 (absmax 0.0 x4):
// a_d += e[k0+4q+d]*Wx[k0+4q+d][col], q ascending; own=(a0+a1)+(a2+a3);
// full = bj + (own + swz16(own)); store by p==0 lanes.
// Streamed loads (no buffer arrays) keep VGPR ~130 -> 3 resident waves/SIMD.
__global__ __launch_bounds__(256, 3) void embproj_kernel(
    const float* __restrict__ emb, const float* __restrict__ Wx,
    const float* __restrict__ brnn, float* __restrict__ embP)
{
    int tid  = threadIdx.x;
    int wv   = tid >> 6;
    int l    = tid & 63;
    int j16  = l & 15;
    int p    = (l >> 4) & 1;
    int g    = l >> 5;
    int col  = j16 + 16 * g;
    int colc = (col < HID) ? col : (HID - 1);
    int k0   = 64 * p;

    float whx[64];
    #pragma unroll
    for (int i = 0; i < 64; ++i)
        whx[i] = Wx[(k0 + i) * HID + colc];
    float bj = brnn[colc];

    int base = (blockIdx.x * 4 + wv) * 6;   // 6 rows per wave

    #pragma unroll 2
    for (int r = 0; r < 6; ++r) {
        int v  = base + r;
        int vc = min(v, VOCAB - 1);
        const f4ma* e4 = (const f4ma*)(emb + (size_t)vc * EMBED + k0);
        float a0 = 0.f, a1 = 0.f, a2 = 0.f, a3 = 0.f;
        #pragma unroll
        for (int q = 0; q < 16; ++q) {
            float4 e = e4[q];
            a0 += e.x * whx[4*q+0];
            a1 += e.y * whx[4*q+1];
            a2 += e.z * whx[4*q+2];
            a3 += e.w * whx[4*q+3];
        }
        float own  = (a0 + a1) + (a2 + a3);
        float full = bj + (own + swz16_f(own));
        if (p == 0 && col < HID && v < VOCAB)
            embP[(size_t)v * HID + col] = full;
    }
}

// Kernel 2: fused RNN recurrence + dense head. BYTE-IDENTICAL to r18
// (champion, ~71.5us, absmax 0.0). Do not touch.
__global__ __launch_bounds__(128) void rnn_head_kernel(
    const int* __restrict__ tokens, const float* __restrict__ embP,
    const float* __restrict__ Wh,
    const float* __restrict__ W1, const float* __restrict__ b1,
    const float* __restrict__ W2, const float* __restrict__ b2,
    const float* __restrict__ W3, const float* __restrict__ b3,
    const float* __restrict__ Wo, const float* __restrict__ bo,
    float* __restrict__ out)
{
    __shared__ __align__(16) float hL[4][32];
    __shared__ float d1L[4][128];
    __shared__ float d2L[4][64];

    int tid  = threadIdx.x;
    int wv   = tid >> 6;            // wave 0..1
    int l    = tid & 63;
    int j16  = l & 15;
    int row  = (l >> 4) & 1;        // row within wave (bit 4)
    int p    = l >> 5;              // k-half (bit 5) -> partner = l^32
    int j    = j16 + 16 * p;        // own column
    int rloc = wv * 2 + row;        // row within block, 0..3
    int b    = blockIdx.x * 4 + rloc;

    const int* trow = tokens + (size_t)b * SEQ;
    int jc = (j < HID) ? j : (HID - 1);

    hL[rloc][j] = 0.0f;             // h0 = 0
    __builtin_amdgcn_sched_barrier(0);

    // permlane32_swap direction probe (r18-proven)
    bool useR0;
    {
        unsigned li = (unsigned)l;
        uint2v rp = __builtin_amdgcn_permlane32_swap(li, li, false, false);
        useR0 = (rp[0] == (unsigned)(l ^ 32));
    }

    int cB = j16 + 16;
    float whA[16], whB[16];
    #pragma unroll
    for (int kk = 0; kk < 16; ++kk) {
        int k = 16 * p + kk;
        whA[kk] = (k < HID) ? Wh[k * HID + j16] : 0.0f;
        whB[kk] = (k < HID && cB < HID) ? Wh[k * HID + cB] : 0.0f;
    }

    float xq[8]; int tr[8];
    #pragma unroll
    for (int s = 0; s < 8; ++s) {
        xq[s] = embP[(size_t)trow[s] * HID + jc];
        tr[s] = trow[8 + s];
    }

    for (int t = 0; t < SEQ; t += 8) {
        #pragma unroll
        for (int s = 0; s < 8; ++s) {
            float hv[16];
            const f4ma* h4 = (const f4ma*)(&hL[rloc][16 * p]);
            #pragma unroll
            for (int qq = 0; qq < 4; ++qq) {
                f4ma hh = h4[qq];
                hv[4*qq+0] = hh.x; hv[4*qq+1] = hh.y;
                hv[4*qq+2] = hh.z; hv[4*qq+3] = hh.w;
            }
            float xp = xq[s];
            xq[s] = embP[(size_t)tr[s] * HID + jc];
            int tn = t + 16 + s; tn = (tn < SEQ) ? tn : SEQ - 1;
            tr[s] = trow[tn];

            float a0=0.f, a1=0.f, b0=0.f, b1=0.f;
            #pragma unroll
            for (int kk = 0; kk < 16; kk += 2) {
                a0 += hv[kk]   * whA[kk];
                a1 += hv[kk+1] * whA[kk+1];
                b0 += hv[kk]   * whB[kk];
                b1 += hv[kk+1] * whB[kk+1];
            }
            float pA = a0 + a1;
            float pB = b0 + b1;
            float own  = p ? pB : pA;
            float send = p ? pA : pB;
            unsigned si = __float_as_uint(send);
            uint2v sw = __builtin_amdgcn_permlane32_swap(si, si, false, false);
            float recv = __uint_as_float(useR0 ? sw[0] : sw[1]);
            float hn = tanh_fast(xp + (own + recv));
            if (j < HID) hL[rloc][j] = hn;
            __builtin_amdgcn_sched_barrier(0);
        }
    }

    {
        int half = l >> 5, j32 = l & 31;
        int rh = wv * 2 + half;
        int bB = blockIdx.x * 4 + rh;
        #pragma unroll
        for (int qq = 0; qq < 4; ++qq) {
            int c = j32 + 32 * qq;
            float acc = b1[c];
            #pragma unroll
            for (int k = 0; k < HID; ++k) acc += hL[rh][k] * W1[k * 128 + c];
            d1L[rh][c] = fmaxf(acc, 0.0f);
        }
        #pragma unroll
        for (int qq = 0; qq < 2; ++qq) {
            int c = j32 + 32 * qq;
            float acc = b2[c];
            #pragma unroll 8
            for (int k = 0; k < 128; ++k) acc += d1L[rh][k] * W2[k * 64 + c];
            d2L[rh][c] = fmaxf(acc, 0.0f);
        }
        float acc3 = b3[j32];
        #pragma unroll 8
        for (int k = 0; k < 64; ++k) acc3 += d2L[rh][k] * W3[k * 32 + j32];
        acc3 = fmaxf(acc3, 0.0f);
        float prod = acc3 * Wo[j32];
        #pragma unroll
        for (int m = 16; m > 0; m >>= 1) prod += __shfl_xor(prod, m, 32);
        if (j32 == 0) out[bB] = 1.0f / (1.0f + __expf(-(prod + bo[0])));
    }
}

extern "C" void kernel_launch(void* const* d_in, const int* in_sizes, int n_in,
                              void* d_out, int out_size, void* d_ws, size_t ws_size,
                              hipStream_t stream) {
    (void)in_sizes; (void)n_in; (void)out_size; (void)ws_size;
    const int*   tokens = (const int*)  d_in[0];
    const float* emb    = (const float*)d_in[1];
    const float* Wx     = (const float*)d_in[2];
    const float* Wh     = (const float*)d_in[3];
    const float* brnn   = (const float*)d_in[4];
    const float* W1     = (const float*)d_in[5];
    const float* b1     = (const float*)d_in[6];
    const float* W2     = (const float*)d_in[7];
    const float* b2     = (const float*)d_in[8];
    const float* W3     = (const float*)d_in[9];
    const float* b3     = (const float*)d_in[10];
    const float* Wo     = (const float*)d_in[11];
    const float* bo     = (const float*)d_in[12];
    float* out  = (float*)d_out;
    float* embP = (float*)d_ws;   // 50000*30*4 = 6 MB

    // 2084 blocks x 4 waves x 6 rows = 50016 rows >= VOCAB
    embproj_kernel<<<2084, 256, 0, stream>>>(emb, Wx, brnn, embP);
    rnn_head_kernel<<<BATCH / 4, 128, 0, stream>>>(
        tokens, embP, Wh, W1, b1, W2, b2, W3, b3, Wo, bo, out);
}

// Round 22
// 95.700 us; speedup vs baseline: 1.2345x; 1.1319x over previous
//
#include <hip/hip_runtime.h>
#include <math.h>

#define VOCAB 50000
#define EMBED 128
#define SEQ   200
#define HID   30
#define BATCH 4096

// CHAMPION CONFIG (r18, 95.77us, absmax 0.0) — verbatim revert from r21's
// regression (108.3us). Ledger: rnn transport variants (r13/r16/r17/r18/r19)
// span 71-85us with +-10% cross-round noise (r21: byte-identical rnn moved
// 71.5->80 on predecessor-grid change alone); embproj ~22-26us across FOUR
// structures (VMEM count, FMA count, LDS, residency all non-binding).
// No pipe saturated (VALU ~60%, LDS ~56%, HBM 7%) => latency-bound serial
// recurrence; this decomposition's floor is this file.
typedef float4 __attribute__((__may_alias__)) f4ma;
typedef unsigned int uint2v __attribute__((ext_vector_type(2)));

__device__ __forceinline__ float tanh_fast(float x) {
    float e = __expf(2.0f * x);
    return 1.0f - __fdividef(2.0f, e + 1.0f);
}
__device__ __forceinline__ float swz16_f(float x) {   // lane ^= 16
    return __int_as_float(__builtin_amdgcn_ds_swizzle(__float_as_int(x), 0x401F));
}

// Kernel 1: embP[v][j] = sum_e emb[v][e]*Wx[e][j] + b_rnn[j]
// r16 version verbatim (the one co-measured in the 95.8us champion run).
__global__ __launch_bounds__(256, 2) void embproj_kernel(
    const float* __restrict__ emb, const float* __restrict__ Wx,
    const float* __restrict__ brnn, float* __restrict__ embP)
{
    int tid  = threadIdx.x;
    int wv   = tid >> 6;
    int l    = tid & 63;
    int j16  = l & 15;
    int p    = (l >> 4) & 1;
    int g    = l >> 5;
    int col  = j16 + 16 * g;
    int colc = (col < HID) ? col : (HID - 1);
    int k0   = 64 * p;

    float whx[64];
    #pragma unroll
    for (int i = 0; i < 64; ++i)
        whx[i] = Wx[(k0 + i) * HID + colc];
    float bj = brnn[colc];

    int base = (blockIdx.x * 4 + wv) * 25;

    float4 eA[16], eB[16];
    #define LOADROW(dst, v) { \
        int vc = min((v), VOCAB - 1); \
        const f4ma* e4 = (const f4ma*)(emb + (size_t)vc * EMBED + k0); \
        _Pragma("unroll") \
        for (int q = 0; q < 16; ++q) dst[q] = e4[q]; \
    }
    #define COMPUTE(src, v) { \
        float a0 = 0.f, a1 = 0.f, a2 = 0.f, a3 = 0.f; \
        _Pragma("unroll") \
        for (int q = 0; q < 16; ++q) { \
            a0 += src[q].x * whx[4*q+0]; \
            a1 += src[q].y * whx[4*q+1]; \
            a2 += src[q].z * whx[4*q+2]; \
            a3 += src[q].w * whx[4*q+3]; \
        } \
        float own  = (a0 + a1) + (a2 + a3); \
        float full = bj + (own + swz16_f(own)); \
        if (p == 0 && col < HID && (v) < VOCAB) \
            embP[(size_t)(v) * HID + col] = full; \
    }

    LOADROW(eA, base + 0);
    for (int r = 0; r < 25; r += 2) {
        LOADROW(eB, base + r + 1);
        COMPUTE(eA, base + r);
        LOADROW(eA, base + r + 2);
        COMPUTE(eB, base + r + 1);
    }
    #undef LOADROW
    #undef COMPUTE
}

// Kernel 2: fused RNN recurrence + dense head. r18 champion verbatim.
__global__ __launch_bounds__(128) void rnn_head_kernel(
    const int* __restrict__ tokens, const float* __restrict__ embP,
    const float* __restrict__ Wh,
    const float* __restrict__ W1, const float* __restrict__ b1,
    const float* __restrict__ W2, const float* __restrict__ b2,
    const float* __restrict__ W3, const float* __restrict__ b3,
    const float* __restrict__ Wo, const float* __restrict__ bo,
    float* __restrict__ out)
{
    __shared__ __align__(16) float hL[4][32];
    __shared__ float d1L[4][128];
    __shared__ float d2L[4][64];

    int tid  = threadIdx.x;
    int wv   = tid >> 6;            // wave 0..1
    int l    = tid & 63;
    int j16  = l & 15;
    int row  = (l >> 4) & 1;        // row within wave (bit 4)
    int p    = l >> 5;              // k-half (bit 5) -> partner = l^32
    int j    = j16 + 16 * p;        // own column
    int rloc = wv * 2 + row;        // row within block, 0..3
    int b    = blockIdx.x * 4 + rloc;

    const int* trow = tokens + (size_t)b * SEQ;
    int jc = (j < HID) ? j : (HID - 1);

    hL[rloc][j] = 0.0f;             // h0 = 0
    __builtin_amdgcn_sched_barrier(0);

    // permlane32_swap direction probe
    bool useR0;
    {
        unsigned li = (unsigned)l;
        uint2v rp = __builtin_amdgcn_permlane32_swap(li, li, false, false);
        useR0 = (rp[0] == (unsigned)(l ^ 32));
    }

    int cB = j16 + 16;
    float whA[16], whB[16];
    #pragma unroll
    for (int kk = 0; kk < 16; ++kk) {
        int k = 16 * p + kk;
        whA[kk] = (k < HID) ? Wh[k * HID + j16] : 0.0f;
        whB[kk] = (k < HID && cB < HID) ? Wh[k * HID + cB] : 0.0f;
    }

    float xq[8]; int tr[8];
    #pragma unroll
    for (int s = 0; s < 8; ++s) {
        xq[s] = embP[(size_t)trow[s] * HID + jc];
        tr[s] = trow[8 + s];
    }

    for (int t = 0; t < SEQ; t += 8) {
        #pragma unroll
        for (int s = 0; s < 8; ++s) {
            float hv[16];
            const f4ma* h4 = (const f4ma*)(&hL[rloc][16 * p]);
            #pragma unroll
            for (int qq = 0; qq < 4; ++qq) {
                f4ma hh = h4[qq];
                hv[4*qq+0] = hh.x; hv[4*qq+1] = hh.y;
                hv[4*qq+2] = hh.z; hv[4*qq+3] = hh.w;
            }
            float xp = xq[s];
            xq[s] = embP[(size_t)tr[s] * HID + jc];
            int tn = t + 16 + s; tn = (tn < SEQ) ? tn : SEQ - 1;
            tr[s] = trow[tn];

            float a0=0.f, a1=0.f, b0=0.f, b1=0.f;
            #pragma unroll
            for (int kk = 0; kk < 16; kk += 2) {
                a0 += hv[kk]   * whA[kk];
                a1 += hv[kk+1] * whA[kk+1];
                b0 += hv[kk]   * whB[kk];
                b1 += hv[kk+1] * whB[kk+1];
            }
            float pA = a0 + a1;
            float pB = b0 + b1;
            float own  = p ? pB : pA;
            float send = p ? pA : pB;
            unsigned si = __float_as_uint(send);
            uint2v sw = __builtin_amdgcn_permlane32_swap(si, si, false, false);
            float recv = __uint_as_float(useR0 ? sw[0] : sw[1]);
            float hn = tanh_fast(xp + (own + recv));
            if (j < HID) hL[rloc][j] = hn;
            __builtin_amdgcn_sched_barrier(0);
        }
    }

    {
        int half = l >> 5, j32 = l & 31;
        int rh = wv * 2 + half;
        int bB = blockIdx.x * 4 + rh;
        #pragma unroll
        for (int qq = 0; qq < 4; ++qq) {
            int c = j32 + 32 * qq;
            float acc = b1[c];
            #pragma unroll
            for (int k = 0; k < HID; ++k) acc += hL[rh][k] * W1[k * 128 + c];
            d1L[rh][c] = fmaxf(acc, 0.0f);
        }
        #pragma unroll
        for (int qq = 0; qq < 2; ++qq) {
            int c = j32 + 32 * qq;
            float acc = b2[c];
            #pragma unroll 8
            for (int k = 0; k < 128; ++k) acc += d1L[rh][k] * W2[k * 64 + c];
            d2L[rh][c] = fmaxf(acc, 0.0f);
        }
        float acc3 = b3[j32];
        #pragma unroll 8
        for (int k = 0; k < 64; ++k) acc3 += d2L[rh][k] * W3[k * 32 + j32];
        acc3 = fmaxf(acc3, 0.0f);
        float prod = acc3 * Wo[j32];
        #pragma unroll
        for (int m = 16; m > 0; m >>= 1) prod += __shfl_xor(prod, m, 32);
        if (j32 == 0) out[bB] = 1.0f / (1.0f + __expf(-(prod + bo[0])));
    }
}

extern "C" void kernel_launch(void* const* d_in, const int* in_sizes, int n_in,
                              void* d_out, int out_size, void* d_ws, size_t ws_size,
                              hipStream_t stream) {
    (void)in_sizes; (void)n_in; (void)out_size; (void)ws_size;
    const int*   tokens = (const int*)  d_in[0];
    const float* emb    = (const float*)d_in[1];
    const float* Wx     = (const float*)d_in[2];
    const float* Wh     = (const float*)d_in[3];
    const float* brnn   = (const float*)d_in[4];
    const float* W1     = (const float*)d_in[5];
    const float* b1     = (const float*)d_in[6];
    const float* W2     = (const float*)d_in[7];
    const float* b2     = (const float*)d_in[8];
    const float* W3     = (const float*)d_in[9];
    const float* b3     = (const float*)d_in[10];
    const float* Wo     = (const float*)d_in[11];
    const float* bo     = (const float*)d_in[12];
    float* out  = (float*)d_out;
    float* embP = (float*)d_ws;   // 50000*30*4 = 6 MB

    embproj_kernel<<<512, 256, 0, stream>>>(emb, Wx, brnn, embP);
    rnn_head_kernel<<<BATCH / 4, 128, 0, stream>>>(
        tokens, embP, Wh, W1, b1, W2, b2, W3, b3, Wo, bo, out);
}